// Round 1
// baseline (3944.832 us; speedup 1.0000x reference)
//
#include <hip/hip_runtime.h>

#define N_NODES 20000
#define N_EDGES 640000
#define D 128
#define H 128

// LDS strides (floats). SEIN: 257-wide input rows padded to 260 (16B-aligned rows,
// row stride %32 banks = 4 -> 2-way conflict = free). SOUT: 128+4. SW: 32+4.
#define SEIN 260
#define SOUT 132
#define SW   36

__device__ __forceinline__ float silu_f(float x) {
    return x / (1.0f + __expf(-x));
}

// Accumulate acc[4][8] += IN[64][ktot] @ W[128][wrow]^T over k in [0,ktot).
// IN is LDS (row stride sistride), W is global row-major with row stride wrow.
// Thread (er = tid&15, oc = tid>>4) owns edges er+16i, outputs oc+16j.
__device__ __forceinline__ void gemm_acc(
    const float* __restrict__ W, int wrow,
    const float* sin_, int sistride, int ktot,
    float acc[4][8], float* wch, int er, int oc, int tid)
{
    for (int kc0 = 0; kc0 < ktot; kc0 += 32) {
        // stage weight chunk: wch[o][kk] = W[o][kc0+kk]; coalesced global,
        // conflict-free LDS writes.
        #pragma unroll
        for (int it = 0; it < 16; ++it) {
            int idx = tid + it * 256;
            int o = idx >> 5, kk = idx & 31;
            wch[o * SW + kk] = W[o * wrow + kc0 + kk];
        }
        __syncthreads();
        #pragma unroll
        for (int kk = 0; kk < 32; kk += 4) {
            float4 a[4], b[8];
            #pragma unroll
            for (int i = 0; i < 4; ++i)
                a[i] = *(const float4*)&sin_[(er + 16 * i) * sistride + kc0 + kk];
            #pragma unroll
            for (int j = 0; j < 8; ++j)
                b[j] = *(const float4*)&wch[(oc + 16 * j) * SW + kk];
            #pragma unroll
            for (int i = 0; i < 4; ++i)
                #pragma unroll
                for (int j = 0; j < 8; ++j)
                    acc[i][j] += a[i].x * b[j].x + a[i].y * b[j].y
                               + a[i].z * b[j].z + a[i].w * b[j].w;
        }
        __syncthreads();
    }
}

__device__ __forceinline__ void zero_acc(float acc[4][8]) {
    #pragma unroll
    for (int i = 0; i < 4; ++i)
        #pragma unroll
        for (int j = 0; j < 8; ++j) acc[i][j] = 0.f;
}

// epilogue: out[e][o] = silu(acc + bias[o])
__device__ __forceinline__ void epi_silu(float acc[4][8], const float* __restrict__ bias,
                                         float* out, int er, int oc)
{
    #pragma unroll
    for (int j = 0; j < 8; ++j) {
        int o = oc + 16 * j;
        float b = bias[o];
        #pragma unroll
        for (int i = 0; i < 4; ++i)
            out[(er + 16 * i) * SOUT + o] = silu_f(acc[i][j] + b);
    }
}

__global__ void egcl_init(const float* __restrict__ coord,
                          float* __restrict__ hout, float* __restrict__ cout)
{
    int idx = blockIdx.x * 256 + threadIdx.x;
    if (idx < N_NODES * D) hout[idx] = 0.f;
    int idx2 = idx - N_NODES * D;
    if (idx2 >= 0 && idx2 < N_NODES * 3) cout[idx2] = coord[idx2];
}

__global__ __launch_bounds__(256)
void egcl_edge(const float* __restrict__ h, const float* __restrict__ coord,
               const int* __restrict__ eidx,
               const float* __restrict__ We1, const float* __restrict__ be1,
               const float* __restrict__ We2, const float* __restrict__ be2,
               const float* __restrict__ Wc1, const float* __restrict__ bc1,
               const float* __restrict__ Wc2,
               float* __restrict__ agg, float* __restrict__ coord_out)
{
    __shared__ __align__(16) float ein[64 * SEIN];
    __shared__ __align__(16) float t1 [64 * SOUT];
    __shared__ __align__(16) float ef [64 * SOUT];
    __shared__ __align__(16) float wch[128 * SW];
    __shared__ float cd[64 * 4];
    __shared__ float wco[64];
    __shared__ float wc2s[128];
    __shared__ int   srcs[64];

    const int tid = threadIdx.x;
    const int e0 = blockIdx.x * 64;
    const int wv = tid >> 6, ln = tid & 63;
    const int er = tid & 15, oc = tid >> 4;

    if (tid < 128) wc2s[tid] = Wc2[tid];

    // stage e_in = [h[src] | h[dst] | radial]; each wave stages 16 edges.
    for (int t = 0; t < 16; ++t) {
        int el = wv * 16 + t;
        int e  = e0 + el;
        int s  = eidx[e];
        int d  = eidx[N_EDGES + e];
        const float* hs = h + s * D;
        const float* hd = h + d * D;
        ein[el * SEIN +       ln] = hs[ln];
        ein[el * SEIN +  64 + ln] = hs[64 + ln];
        ein[el * SEIN + 128 + ln] = hd[ln];
        ein[el * SEIN + 192 + ln] = hd[64 + ln];
        if (ln == 0) {
            srcs[el] = s;
            float dx = coord[s * 3 + 0] - coord[d * 3 + 0];
            float dy = coord[s * 3 + 1] - coord[d * 3 + 1];
            float dz = coord[s * 3 + 2] - coord[d * 3 + 2];
            cd[el * 4 + 0] = dx; cd[el * 4 + 1] = dy; cd[el * 4 + 2] = dz;
            ein[el * SEIN + 256] = dx * dx + dy * dy + dz * dz;
        }
    }
    __syncthreads();

    float acc[4][8];

    // GEMM1: e_in[64][257] @ We1^T -> silu -> t1
    zero_acc(acc);
    gemm_acc(We1, 257, ein, SEIN, 256, acc, wch, er, oc, tid);
    {   // k = 256 tail (radial column)
        float ar[4];
        #pragma unroll
        for (int i = 0; i < 4; ++i) ar[i] = ein[(er + 16 * i) * SEIN + 256];
        #pragma unroll
        for (int j = 0; j < 8; ++j) {
            float w2 = We1[(oc + 16 * j) * 257 + 256];
            #pragma unroll
            for (int i = 0; i < 4; ++i) acc[i][j] += ar[i] * w2;
        }
    }
    epi_silu(acc, be1, t1, er, oc);

    // GEMM2: t1 @ We2^T -> silu -> ef (edge_feat)
    zero_acc(acc);
    gemm_acc(We2, 128, t1, SOUT, 128, acc, wch, er, oc, tid);
    epi_silu(acc, be2, ef, er, oc);

    // GEMM3: ef @ Wc1^T -> silu -> c1 (reuse t1 buffer)
    zero_acc(acc);
    gemm_acc(Wc1, 128, ef, SOUT, 128, acc, wch, er, oc, tid);
    epi_silu(acc, bc1, t1, er, oc);
    __syncthreads();

    // per-edge coord weight: w = c1[e] . Wc2
    {
        int e = tid >> 2, q = tid & 3;
        const float* c1r = &t1[e * SOUT];
        float s_ = 0.f;
        #pragma unroll
        for (int k = 0; k < 32; ++k) s_ += c1r[q * 32 + k] * wc2s[q * 32 + k];
        s_ += __shfl_down(s_, 2);
        s_ += __shfl_down(s_, 1);
        if (q == 0) wco[e] = s_;
    }
    __syncthreads();

    // coord scatter: coord_out[src] += coord_diff * w
    if (tid < 192) {
        int e = tid / 3, c = tid - (tid / 3) * 3;
        atomicAdd(&coord_out[srcs[e] * 3 + c], cd[e * 4 + c] * wco[e]);
    }
    // agg scatter: agg[src] += edge_feat
    #pragma unroll
    for (int p = 0; p < 32; ++p) {
        int e = (tid >> 7) + p * 2;
        int o = tid & 127;
        atomicAdd(&agg[srcs[e] * D + o], ef[e * SOUT + o]);
    }
}

__global__ __launch_bounds__(256)
void egcl_node(const float* __restrict__ h,
               const float* __restrict__ Wn1, const float* __restrict__ bn1,
               const float* __restrict__ Wn2, const float* __restrict__ bn2,
               float* __restrict__ hout /* holds agg on entry */)
{
    __shared__ __align__(16) float nin[64 * SEIN];
    __shared__ __align__(16) float t1 [64 * SOUT];
    __shared__ __align__(16) float wch[128 * SW];

    const int tid = threadIdx.x;
    const int n0 = blockIdx.x * 64;
    const int wv = tid >> 6, ln = tid & 63;
    const int er = tid & 15, oc = tid >> 4;

    for (int t = 0; t < 16; ++t) {
        int nl = wv * 16 + t;
        int n = n0 + nl; if (n >= N_NODES) n = N_NODES - 1;
        nin[nl * SEIN +       ln] = h[n * D + ln];
        nin[nl * SEIN +  64 + ln] = h[n * D + 64 + ln];
        nin[nl * SEIN + 128 + ln] = hout[n * D + ln];
        nin[nl * SEIN + 192 + ln] = hout[n * D + 64 + ln];
    }
    __syncthreads();

    float acc[4][8];
    zero_acc(acc);
    gemm_acc(Wn1, 256, nin, SEIN, 256, acc, wch, er, oc, tid);
    epi_silu(acc, bn1, t1, er, oc);

    zero_acc(acc);
    gemm_acc(Wn2, 128, t1, SOUT, 128, acc, wch, er, oc, tid);
    #pragma unroll
    for (int j = 0; j < 8; ++j) {
        int o = oc + 16 * j;
        float b = bn2[o];
        #pragma unroll
        for (int i = 0; i < 4; ++i) {
            int n = n0 + er + 16 * i;
            if (n < N_NODES)
                hout[n * D + o] = h[n * D + o] + acc[i][j] + b;
        }
    }
}

extern "C" void kernel_launch(void* const* d_in, const int* in_sizes, int n_in,
                              void* d_out, int out_size, void* d_ws, size_t ws_size,
                              hipStream_t stream)
{
    const float* h     = (const float*)d_in[0];
    const float* coord = (const float*)d_in[1];
    const int*   eidx  = (const int*)d_in[2];
    const float* We1 = (const float*)d_in[3];
    const float* be1 = (const float*)d_in[4];
    const float* We2 = (const float*)d_in[5];
    const float* be2 = (const float*)d_in[6];
    const float* Wn1 = (const float*)d_in[7];
    const float* bn1 = (const float*)d_in[8];
    const float* Wn2 = (const float*)d_in[9];
    const float* bn2 = (const float*)d_in[10];
    const float* Wc1 = (const float*)d_in[11];
    const float* bc1 = (const float*)d_in[12];
    const float* Wc2 = (const float*)d_in[13];

    float* hout = (float*)d_out;                       // h_out; doubles as agg accumulator
    float* cout = (float*)d_out + (size_t)N_NODES * D; // coord_out

    int tot = N_NODES * (D + 3);
    egcl_init<<<(tot + 255) / 256, 256, 0, stream>>>(coord, hout, cout);
    egcl_edge<<<N_EDGES / 64, 256, 0, stream>>>(h, coord, eidx,
                                                We1, be1, We2, be2, Wc1, bc1, Wc2,
                                                hout, cout);
    egcl_node<<<(N_NODES + 63) / 64, 256, 0, stream>>>(h, Wn1, bn1, Wn2, bn2, hout);
}

// Round 2
// 767.634 us; speedup vs baseline: 5.1389x; 5.1389x over previous
//
#include <hip/hip_runtime.h>

#define N_NODES 20000
#define N_EDGES 640000
#define D 128
#define H 128

// ---------------- MFMA edge kernel config ----------------
#define EB  128           // edges per block
#define TPB 512           // 8 waves
#define SA  264           // ein row stride (bf16): 528B == 16 mod 128 -> conflict-free b128
#define ST  136           // t1/ef row stride (bf16): 272B == 16 mod 128
#define SWC 32            // weight chunk row stride (bf16): 64B rows, uniform banks

typedef short bf16x8 __attribute__((ext_vector_type(8)));
typedef float f32x4  __attribute__((ext_vector_type(4)));

__device__ __forceinline__ float silu_f(float x) { return x / (1.0f + __expf(-x)); }

__device__ __forceinline__ ushort f2b(float f) {          // f32 -> bf16 RNE
    union { float f; unsigned int u; } v; v.f = f;
    return (ushort)((v.u + 0x7FFF + ((v.u >> 16) & 1)) >> 16);
}
__device__ __forceinline__ float b2f(ushort s) {
    union { unsigned int u; float f; } v; v.u = ((unsigned int)s) << 16; return v.f;
}

// stage a 128x32 f32 weight chunk (row stride wrow) into LDS as bf16
__device__ __forceinline__ void stage_w(ushort* wb, const float* __restrict__ W,
                                        int wrow, int kc0, int tid) {
    #pragma unroll
    for (int it = 0; it < 8; ++it) {
        int idx = tid + it * TPB;
        int o = idx >> 5, c = idx & 31;
        wb[o * SWC + c] = f2b(W[o * wrow + kc0 + c]);
    }
}

// one K=32 chunk: acc[4][2] += A[64x32] @ W^T[32x32-cols]
__device__ __forceinline__ void gemm_chunk(const ushort* Ab, int astride, int kc0,
                                           const ushort* wb, f32x4 acc[4][2],
                                           int eg, int cg, int lane) {
    const int r = lane & 15, g = lane >> 4;
    bf16x8 a[4], b[2];
    #pragma unroll
    for (int mt = 0; mt < 4; ++mt)
        a[mt] = *(const bf16x8*)&Ab[(eg * 64 + mt * 16 + r) * astride + kc0 + g * 8];
    #pragma unroll
    for (int nt = 0; nt < 2; ++nt)
        b[nt] = *(const bf16x8*)&wb[(cg * 32 + nt * 16 + r) * SWC + g * 8];
    #pragma unroll
    for (int mt = 0; mt < 4; ++mt)
        #pragma unroll
        for (int nt = 0; nt < 2; ++nt)
            acc[mt][nt] = __builtin_amdgcn_mfma_f32_16x16x32_bf16(a[mt], b[nt], acc[mt][nt], 0, 0, 0);
}

__device__ __forceinline__ void zero_acc8(f32x4 acc[4][2]) {
    #pragma unroll
    for (int mt = 0; mt < 4; ++mt)
        #pragma unroll
        for (int nt = 0; nt < 2; ++nt)
            acc[mt][nt] = (f32x4){0.f, 0.f, 0.f, 0.f};
}

// epilogue: out[e][o] = bf16(silu(acc + bias[o]))
__device__ __forceinline__ void epi_silu8(f32x4 acc[4][2], const float* bias,
                                          ushort* out, int ostride,
                                          int eg, int cg, int lane) {
    const int r = lane & 15, g = lane >> 4;
    #pragma unroll
    for (int nt = 0; nt < 2; ++nt) {
        int o = cg * 32 + nt * 16 + r;
        float bo = bias[o];
        #pragma unroll
        for (int mt = 0; mt < 4; ++mt)
            #pragma unroll
            for (int j = 0; j < 4; ++j) {
                int e = eg * 64 + mt * 16 + g * 4 + j;
                out[e * ostride + o] = f2b(silu_f(acc[mt][nt][j] + bo));
            }
    }
}

__global__ void egcl_init(const float* __restrict__ coord,
                          float* __restrict__ hout, float* __restrict__ cout)
{
    int idx = blockIdx.x * 256 + threadIdx.x;
    if (idx < N_NODES * D) hout[idx] = 0.f;
    int idx2 = idx - N_NODES * D;
    if (idx2 >= 0 && idx2 < N_NODES * 3) cout[idx2] = coord[idx2];
}

__global__ __launch_bounds__(TPB)
void egcl_edge(const float* __restrict__ h, const float* __restrict__ coord,
               const int* __restrict__ eidx,
               const float* __restrict__ We1, const float* __restrict__ be1,
               const float* __restrict__ We2, const float* __restrict__ be2,
               const float* __restrict__ Wc1, const float* __restrict__ bc1,
               const float* __restrict__ Wc2,
               float* __restrict__ agg, float* __restrict__ coord_out)
{
    __shared__ __align__(16) ushort ein[EB * SA];        // 67.6 KB; ef overlays after GEMM1
    __shared__ __align__(16) ushort t1 [EB * ST];        // 34.8 KB; c1 overlays after GEMM2
    __shared__ __align__(16) ushort wch[2][128 * SWC];   // 16 KB double-buffered
    __shared__ float radial_f[EB], w256[H], b1s[H], b2s[H], bc1s[H], wc2s[H];
    __shared__ float cdx[EB], cdy[EB], cdz[EB], wco[EB];
    __shared__ int   srcs[EB], dsts[EB];

    ushort* const ef = ein;   // stride ST, 34.8 KB <= ein region

    const int tid  = threadIdx.x;
    const int lane = tid & 63;
    const int wv   = tid >> 6;
    const int eg   = wv >> 2;        // 0..1: edge group (64 edges)
    const int cg   = wv & 3;         // 0..3: col group (32 cols)
    const int e0   = blockIdx.x * EB;

    // ---- prologue: indices, coord_diff, radial, small weights ----
    if (tid < EB) {
        int e = e0 + tid;
        int s = eidx[e], d = eidx[N_EDGES + e];
        srcs[tid] = s; dsts[tid] = d;
        float dx = coord[s * 3 + 0] - coord[d * 3 + 0];
        float dy = coord[s * 3 + 1] - coord[d * 3 + 1];
        float dz = coord[s * 3 + 2] - coord[d * 3 + 2];
        cdx[tid] = dx; cdy[tid] = dy; cdz[tid] = dz;
        radial_f[tid] = dx * dx + dy * dy + dz * dz;
    } else if (tid < 256) {
        int o = tid - 128; w256[o] = We1[o * 257 + 256]; b1s[o] = be1[o];
    } else if (tid < 384) {
        int o = tid - 256; b2s[o] = be2[o]; bc1s[o] = bc1[o];
    } else {
        int o = tid - 384; wc2s[o] = Wc2[o];
    }
    __syncthreads();

    // ---- stage e_in = [h[src] | h[dst]] as bf16 ----
    #pragma unroll
    for (int half = 0; half < 2; ++half) {
        #pragma unroll
        for (int it = 0; it < 8; ++it) {
            int idx = tid + it * TPB;
            int e = idx >> 5, c = idx & 31;
            int node = half ? dsts[e] : srcs[e];
            float4 v = *(const float4*)&h[(size_t)node * D + c * 4];
            ushort4 p;
            p.x = f2b(v.x); p.y = f2b(v.y); p.z = f2b(v.z); p.w = f2b(v.w);
            *(ushort4*)&ein[e * SA + half * 128 + c * 4] = p;
        }
    }
    stage_w(wch[0], We1, 257, 0, tid);
    __syncthreads();

    f32x4 acc[4][2];
    const int r = lane & 15, g = lane >> 4;

    // ---- GEMM1: ein[128x256] @ We1[:, :256]^T ----
    zero_acc8(acc);
    for (int kc = 0; kc < 8; ++kc) {
        if (kc < 7) stage_w(wch[(kc + 1) & 1], We1, 257, (kc + 1) * 32, tid);
        gemm_chunk(ein, SA, kc * 32, wch[kc & 1], acc, eg, cg, lane);
        __syncthreads();
    }
    // exact f32 rank-1 radial term (col 256)
    #pragma unroll
    for (int nt = 0; nt < 2; ++nt) {
        int o = cg * 32 + nt * 16 + r;
        float w = w256[o];
        #pragma unroll
        for (int mt = 0; mt < 4; ++mt)
            #pragma unroll
            for (int j = 0; j < 4; ++j) {
                int e = eg * 64 + mt * 16 + g * 4 + j;
                acc[mt][nt][j] += radial_f[e] * w;
            }
    }
    epi_silu8(acc, b1s, t1, ST, eg, cg, lane);
    stage_w(wch[0], We2, 128, 0, tid);
    __syncthreads();

    // ---- GEMM2: t1 @ We2^T -> ef (overlays ein) ----
    zero_acc8(acc);
    for (int kc = 0; kc < 4; ++kc) {
        if (kc < 3) stage_w(wch[(kc + 1) & 1], We2, 128, (kc + 1) * 32, tid);
        gemm_chunk(t1, ST, kc * 32, wch[kc & 1], acc, eg, cg, lane);
        __syncthreads();
    }
    epi_silu8(acc, b2s, ef, ST, eg, cg, lane);
    stage_w(wch[0], Wc1, 128, 0, tid);
    __syncthreads();

    // ---- GEMM3: ef @ Wc1^T -> c1 (overlays t1) ----
    zero_acc8(acc);
    for (int kc = 0; kc < 4; ++kc) {
        if (kc < 3) stage_w(wch[(kc + 1) & 1], Wc1, 128, (kc + 1) * 32, tid);
        gemm_chunk(ef, ST, kc * 32, wch[kc & 1], acc, eg, cg, lane);
        __syncthreads();
    }
    epi_silu8(acc, bc1s, t1, ST, eg, cg, lane);
    __syncthreads();

    // ---- coord weight: wco[e] = c1[e] . Wc2 ----
    {
        int e = tid >> 2, q = tid & 3;
        const ushort* c1r = &t1[e * ST + q * 32];
        float s_ = 0.f;
        #pragma unroll
        for (int k = 0; k < 32; ++k) s_ += b2f(c1r[k]) * wc2s[q * 32 + k];
        s_ += __shfl_down(s_, 2);
        s_ += __shfl_down(s_, 1);
        if (q == 0) wco[e] = s_;
    }
    __syncthreads();

    // ---- scatters ----
    if (tid < 384) {
        int e = tid / 3, c = tid - (tid / 3) * 3;
        float cdv = (c == 0) ? cdx[e] : (c == 1) ? cdy[e] : cdz[e];
        atomicAdd(&coord_out[(size_t)srcs[e] * 3 + c], cdv * wco[e]);
    }
    #pragma unroll
    for (int it = 0; it < 32; ++it) {
        int idx = tid + it * TPB;
        int e = idx >> 7, o = idx & 127;
        atomicAdd(&agg[(size_t)srcs[e] * D + o], b2f(ef[e * ST + o]));
    }
}

// ---------------- f32 node kernel (unchanged from round 1) ----------------
#define NSE 260
#define NSO 132
#define NSW 36

__device__ __forceinline__ void ngemm_acc(
    const float* __restrict__ W, int wrow,
    const float* sin_, int sistride, int ktot,
    float acc[4][8], float* wch, int er, int oc, int tid)
{
    for (int kc0 = 0; kc0 < ktot; kc0 += 32) {
        #pragma unroll
        for (int it = 0; it < 16; ++it) {
            int idx = tid + it * 256;
            int o = idx >> 5, kk = idx & 31;
            wch[o * NSW + kk] = W[o * wrow + kc0 + kk];
        }
        __syncthreads();
        #pragma unroll
        for (int kk = 0; kk < 32; kk += 4) {
            float4 a[4], b[8];
            #pragma unroll
            for (int i = 0; i < 4; ++i)
                a[i] = *(const float4*)&sin_[(er + 16 * i) * sistride + kc0 + kk];
            #pragma unroll
            for (int j = 0; j < 8; ++j)
                b[j] = *(const float4*)&wch[(oc + 16 * j) * NSW + kk];
            #pragma unroll
            for (int i = 0; i < 4; ++i)
                #pragma unroll
                for (int j = 0; j < 8; ++j)
                    acc[i][j] += a[i].x * b[j].x + a[i].y * b[j].y
                               + a[i].z * b[j].z + a[i].w * b[j].w;
        }
        __syncthreads();
    }
}

__global__ __launch_bounds__(256)
void egcl_node(const float* __restrict__ h,
               const float* __restrict__ Wn1, const float* __restrict__ bn1,
               const float* __restrict__ Wn2, const float* __restrict__ bn2,
               float* __restrict__ hout /* holds agg on entry */)
{
    __shared__ __align__(16) float nin[64 * NSE];
    __shared__ __align__(16) float t1 [64 * NSO];
    __shared__ __align__(16) float wch[128 * NSW];

    const int tid = threadIdx.x;
    const int n0 = blockIdx.x * 64;
    const int wv = tid >> 6, ln = tid & 63;
    const int er = tid & 15, oc = tid >> 4;

    for (int t = 0; t < 16; ++t) {
        int nl = wv * 16 + t;
        int n = n0 + nl; if (n >= N_NODES) n = N_NODES - 1;
        nin[nl * NSE +       ln] = h[n * D + ln];
        nin[nl * NSE +  64 + ln] = h[n * D + 64 + ln];
        nin[nl * NSE + 128 + ln] = hout[n * D + ln];
        nin[nl * NSE + 192 + ln] = hout[n * D + 64 + ln];
    }
    __syncthreads();

    float acc[4][8];
    #pragma unroll
    for (int i = 0; i < 4; ++i)
        #pragma unroll
        for (int j = 0; j < 8; ++j) acc[i][j] = 0.f;
    ngemm_acc(Wn1, 256, nin, NSE, 256, acc, wch, er, oc, tid);
    #pragma unroll
    for (int j = 0; j < 8; ++j) {
        int o = oc + 16 * j;
        float b = bn1[o];
        #pragma unroll
        for (int i = 0; i < 4; ++i)
            t1[(er + 16 * i) * NSO + o] = silu_f(acc[i][j] + b);
    }
    __syncthreads();

    #pragma unroll
    for (int i = 0; i < 4; ++i)
        #pragma unroll
        for (int j = 0; j < 8; ++j) acc[i][j] = 0.f;
    ngemm_acc(Wn2, 128, t1, NSO, 128, acc, wch, er, oc, tid);
    #pragma unroll
    for (int j = 0; j < 8; ++j) {
        int o = oc + 16 * j;
        float b = bn2[o];
        #pragma unroll
        for (int i = 0; i < 4; ++i) {
            int n = n0 + er + 16 * i;
            if (n < N_NODES)
                hout[n * D + o] = h[n * D + o] + acc[i][j] + b;
        }
    }
}

extern "C" void kernel_launch(void* const* d_in, const int* in_sizes, int n_in,
                              void* d_out, int out_size, void* d_ws, size_t ws_size,
                              hipStream_t stream)
{
    const float* h     = (const float*)d_in[0];
    const float* coord = (const float*)d_in[1];
    const int*   eidx  = (const int*)d_in[2];
    const float* We1 = (const float*)d_in[3];
    const float* be1 = (const float*)d_in[4];
    const float* We2 = (const float*)d_in[5];
    const float* be2 = (const float*)d_in[6];
    const float* Wn1 = (const float*)d_in[7];
    const float* bn1 = (const float*)d_in[8];
    const float* Wn2 = (const float*)d_in[9];
    const float* bn2 = (const float*)d_in[10];
    const float* Wc1 = (const float*)d_in[11];
    const float* bc1 = (const float*)d_in[12];
    const float* Wc2 = (const float*)d_in[13];

    float* hout = (float*)d_out;                       // h_out; doubles as agg accumulator
    float* cout = (float*)d_out + (size_t)N_NODES * D; // coord_out

    int tot = N_NODES * (D + 3);
    egcl_init<<<(tot + 255) / 256, 256, 0, stream>>>(coord, hout, cout);
    egcl_edge<<<N_EDGES / EB, TPB, 0, stream>>>(h, coord, eidx,
                                                We1, be1, We2, be2, Wc1, bc1, Wc2,
                                                hout, cout);
    egcl_node<<<(N_NODES + 63) / 64, 256, 0, stream>>>(h, Wn1, bn1, Wn2, bn2, hout);
}

// Round 3
// 568.301 us; speedup vs baseline: 6.9415x; 1.3508x over previous
//
#include <hip/hip_runtime.h>

#define N_NODES 20000
#define N_EDGES 640000
#define D 128
#define H 128

#define EB  128           // edges (or nodes) per block
#define TPB 512           // 8 waves
#define SA  264           // input-tile row stride (bf16 shorts)
#define ST  136           // t1/ef row stride
#define SWC 32            // weight chunk row stride (linear, for global_load_lds)

// ---- workspace layout (bytes) ----
#define WS_W1   0         // We1[:, :256] bf16 [128][256]
#define WS_W2   65536     // We2 bf16 [128][128]
#define WS_WC1  98304     // Wc1 bf16 [128][128]
#define WS_WN1  131072    // Wn1 bf16 [128][256]
#define WS_WN2  196608    // Wn2 bf16 [128][128]
#define WS_CNT  229376    // int[20000]
#define WS_CUR  309376    // int[20000]
#define WS_PERM 389376    // int[640000]

typedef short bf16x8 __attribute__((ext_vector_type(8)));
typedef float f32x4  __attribute__((ext_vector_type(4)));

__device__ __forceinline__ float silu_f(float x) { return x / (1.0f + __expf(-x)); }

__device__ __forceinline__ ushort f2b(float f) {          // f32 -> bf16 RNE
    union { float f; unsigned int u; } v; v.f = f;
    return (ushort)((v.u + 0x7FFF + ((v.u >> 16) & 1)) >> 16);
}
__device__ __forceinline__ float b2f(ushort s) {
    union { unsigned int u; float f; } v; v.u = ((unsigned int)s) << 16; return v.f;
}

// async stage of one 128x32 bf16 weight chunk into linear LDS [o][32]
__device__ __forceinline__ void stage_wb(ushort* wb, const ushort* __restrict__ Wb,
                                         int K, int kc0, int tid) {
    int o = tid >> 2, kk = (tid & 3) * 8;
    const ushort* g = Wb + (size_t)o * K + kc0 + kk;
    __builtin_amdgcn_global_load_lds(
        (const __attribute__((address_space(1))) unsigned int*)g,
        (__attribute__((address_space(3))) unsigned int*)(wb + tid * 8),
        16, 0, 0);
}

__device__ __forceinline__ void gemm_chunk(const ushort* Ab, int astride, int kc0,
                                           const ushort* wb, f32x4 acc[4][2],
                                           int eg, int cg, int lane) {
    const int r = lane & 15, g = lane >> 4;
    bf16x8 a[4], b[2];
    #pragma unroll
    for (int mt = 0; mt < 4; ++mt)
        a[mt] = *(const bf16x8*)&Ab[(eg * 64 + mt * 16 + r) * astride + kc0 + g * 8];
    #pragma unroll
    for (int nt = 0; nt < 2; ++nt)
        b[nt] = *(const bf16x8*)&wb[(cg * 32 + nt * 16 + r) * SWC + g * 8];
    #pragma unroll
    for (int mt = 0; mt < 4; ++mt)
        #pragma unroll
        for (int nt = 0; nt < 2; ++nt)
            acc[mt][nt] = __builtin_amdgcn_mfma_f32_16x16x32_bf16(a[mt], b[nt], acc[mt][nt], 0, 0, 0);
}

__device__ __forceinline__ void zero_acc8(f32x4 acc[4][2]) {
    #pragma unroll
    for (int mt = 0; mt < 4; ++mt)
        #pragma unroll
        for (int nt = 0; nt < 2; ++nt)
            acc[mt][nt] = (f32x4){0.f, 0.f, 0.f, 0.f};
}

__device__ __forceinline__ void epi_silu8(f32x4 acc[4][2], const float* bias,
                                          ushort* out, int ostride,
                                          int eg, int cg, int lane) {
    const int r = lane & 15, g = lane >> 4;
    #pragma unroll
    for (int nt = 0; nt < 2; ++nt) {
        int o = cg * 32 + nt * 16 + r;
        float bo = bias[o];
        #pragma unroll
        for (int mt = 0; mt < 4; ++mt)
            #pragma unroll
            for (int j = 0; j < 4; ++j) {
                int e = eg * 64 + mt * 16 + g * 4 + j;
                out[e * ostride + o] = f2b(silu_f(acc[mt][nt][j] + bo));
            }
    }
}

// ---------------- prep: weight bf16 conversion + zeroing ----------------
__global__ void prep(const float* __restrict__ We1, const float* __restrict__ We2,
                     const float* __restrict__ Wc1, const float* __restrict__ Wn1,
                     const float* __restrict__ Wn2, const float* __restrict__ coord,
                     ushort* w1, ushort* w2, ushort* wc1, ushort* wn1, ushort* wn2,
                     int* cnt, float* hout, float* cout)
{
    int idx = blockIdx.x * 256 + threadIdx.x;
    if (idx < 32768) { w1[idx] = f2b(We1[(idx >> 8) * 257 + (idx & 255)]); return; }
    idx -= 32768;
    if (idx < 16384) { w2[idx] = f2b(We2[idx]); return; }
    idx -= 16384;
    if (idx < 16384) { wc1[idx] = f2b(Wc1[idx]); return; }
    idx -= 16384;
    if (idx < 32768) { wn1[idx] = f2b(Wn1[idx]); return; }
    idx -= 32768;
    if (idx < 16384) { wn2[idx] = f2b(Wn2[idx]); return; }
    idx -= 16384;
    if (idx < N_NODES) { cnt[idx] = 0; return; }
    idx -= N_NODES;
    if (idx < N_NODES * D) { hout[idx] = 0.f; return; }
    idx -= N_NODES * D;
    if (idx < N_NODES * 3) cout[idx] = coord[idx];
}

// ---------------- counting sort by src ----------------
__global__ void hist_k(const int* __restrict__ eidx, int* cnt) {
    int e = blockIdx.x * 256 + threadIdx.x;
    if (e < N_EDGES) atomicAdd(&cnt[eidx[e]], 1);
}

__global__ void scan_k(const int* __restrict__ cnt, int* cur) {
    __shared__ int buf[1024];
    __shared__ int carry_s;
    int t = threadIdx.x;
    if (t == 0) carry_s = 0;
    __syncthreads();
    for (int base = 0; base < N_NODES; base += 1024) {
        int v = (base + t < N_NODES) ? cnt[base + t] : 0;
        buf[t] = v; __syncthreads();
        for (int off = 1; off < 1024; off <<= 1) {
            int a = (t >= off) ? buf[t - off] : 0;
            __syncthreads();
            buf[t] += a;
            __syncthreads();
        }
        if (base + t < N_NODES) cur[base + t] = carry_s + buf[t] - v;
        __syncthreads();
        if (t == 0) carry_s += buf[1023];
        __syncthreads();
    }
}

__global__ void scatter_k(const int* __restrict__ eidx, int* cur, int* perm) {
    int e = blockIdx.x * 256 + threadIdx.x;
    if (e < N_EDGES) {
        int p = atomicAdd(&cur[eidx[e]], 1);
        perm[p] = e;
    }
}

// ---------------- fused edge kernel ----------------
__global__ __launch_bounds__(TPB)
void egcl_edge(const float* __restrict__ h, const float* __restrict__ coord,
               const int* __restrict__ eidx, const int* __restrict__ perm,
               const ushort* __restrict__ w1b, const ushort* __restrict__ w2b,
               const ushort* __restrict__ wc1b,
               const float* __restrict__ We1, const float* __restrict__ be1,
               const float* __restrict__ be2, const float* __restrict__ bc1,
               const float* __restrict__ Wc2,
               float* __restrict__ agg, float* __restrict__ coord_out)
{
    __shared__ __align__(16) ushort ein[EB * SA];        // ef overlays after GEMM1
    __shared__ __align__(16) ushort t1 [EB * ST];        // c1 overlays after GEMM2
    __shared__ __align__(16) ushort wch[2][128 * SWC];
    __shared__ float radial_f[EB], w256[H], b1s[H], b2s[H], bc1s[H], wc2s[H];
    __shared__ float cdx[EB], cdy[EB], cdz[EB], wco[EB];
    __shared__ int   srcs[EB], dsts[EB];

    ushort* const ef = ein;

    const int tid  = threadIdx.x;
    const int lane = tid & 63;
    const int wv   = tid >> 6;
    const int eg   = wv >> 2;
    const int cg   = wv & 3;
    const int e0   = blockIdx.x * EB;

    if (tid < EB) {
        int e = perm[e0 + tid];
        int s = eidx[e], d = eidx[N_EDGES + e];
        srcs[tid] = s; dsts[tid] = d;
        float dx = coord[s * 3 + 0] - coord[d * 3 + 0];
        float dy = coord[s * 3 + 1] - coord[d * 3 + 1];
        float dz = coord[s * 3 + 2] - coord[d * 3 + 2];
        cdx[tid] = dx; cdy[tid] = dy; cdz[tid] = dz;
        radial_f[tid] = dx * dx + dy * dy + dz * dz;
    } else if (tid < 256) {
        int o = tid - 128; w256[o] = We1[o * 257 + 256]; b1s[o] = be1[o];
    } else if (tid < 384) {
        int o = tid - 256; b2s[o] = be2[o]; bc1s[o] = bc1[o];
    } else {
        int o = tid - 384; wc2s[o] = Wc2[o];
    }
    __syncthreads();

    // stage e_in = [h[src] | h[dst]] as bf16 (srcs sorted -> heavy L1 reuse)
    #pragma unroll
    for (int half = 0; half < 2; ++half) {
        #pragma unroll
        for (int it = 0; it < 8; ++it) {
            int idx = tid + it * TPB;
            int e = idx >> 5, c = idx & 31;
            int node = half ? dsts[e] : srcs[e];
            float4 v = *(const float4*)&h[(size_t)node * D + c * 4];
            ushort4 p;
            p.x = f2b(v.x); p.y = f2b(v.y); p.z = f2b(v.z); p.w = f2b(v.w);
            *(ushort4*)&ein[e * SA + half * 128 + c * 4] = p;
        }
    }
    stage_wb(wch[0], w1b, 256, 0, tid);
    __syncthreads();

    f32x4 acc[4][2];
    const int r = lane & 15, g = lane >> 4;

    // GEMM1: ein[128x256] @ We1[:, :256]^T
    zero_acc8(acc);
    for (int kc = 0; kc < 8; ++kc) {
        if (kc < 7) stage_wb(wch[(kc + 1) & 1], w1b, 256, (kc + 1) * 32, tid);
        gemm_chunk(ein, SA, kc * 32, wch[kc & 1], acc, eg, cg, lane);
        __syncthreads();
    }
    #pragma unroll
    for (int nt = 0; nt < 2; ++nt) {           // exact f32 radial rank-1 (col 256)
        int o = cg * 32 + nt * 16 + r;
        float w = w256[o];
        #pragma unroll
        for (int mt = 0; mt < 4; ++mt)
            #pragma unroll
            for (int j = 0; j < 4; ++j)
                acc[mt][nt][j] += radial_f[eg * 64 + mt * 16 + g * 4 + j] * w;
    }
    epi_silu8(acc, b1s, t1, ST, eg, cg, lane);
    stage_wb(wch[0], w2b, 128, 0, tid);
    __syncthreads();

    // GEMM2: t1 @ We2^T -> ef
    zero_acc8(acc);
    for (int kc = 0; kc < 4; ++kc) {
        if (kc < 3) stage_wb(wch[(kc + 1) & 1], w2b, 128, (kc + 1) * 32, tid);
        gemm_chunk(t1, ST, kc * 32, wch[kc & 1], acc, eg, cg, lane);
        __syncthreads();
    }
    epi_silu8(acc, b2s, ef, ST, eg, cg, lane);
    stage_wb(wch[0], wc1b, 128, 0, tid);
    __syncthreads();

    // GEMM3: ef @ Wc1^T -> c1
    zero_acc8(acc);
    for (int kc = 0; kc < 4; ++kc) {
        if (kc < 3) stage_wb(wch[(kc + 1) & 1], wc1b, 128, (kc + 1) * 32, tid);
        gemm_chunk(ef, ST, kc * 32, wch[kc & 1], acc, eg, cg, lane);
        __syncthreads();
    }
    epi_silu8(acc, bc1s, t1, ST, eg, cg, lane);
    __syncthreads();

    // wco[e] = c1[e] . Wc2
    {
        int e = tid >> 2, q = tid & 3;
        const ushort* c1r = &t1[e * ST + q * 32];
        float s_ = 0.f;
        #pragma unroll
        for (int k = 0; k < 32; ++k) s_ += b2f(c1r[k]) * wc2s[q * 32 + k];
        s_ += __shfl_down(s_, 2);
        s_ += __shfl_down(s_, 1);
        if (q == 0) wco[e] = s_;
    }
    __syncthreads();

    // segmented agg scatter (srcs sorted): 1 atomic per (run x col x 32-edge chunk)
    {
        int o = tid & 127, q = tid >> 7;
        int base = q * 32;
        float sum = 0.f;
        int cur = srcs[base];
        for (int k = 0; k < 32; ++k) {
            int e = base + k;
            int s = srcs[e];
            if (s != cur) {
                atomicAdd(&agg[(size_t)cur * D + o], sum);
                sum = 0.f; cur = s;
            }
            sum += b2f(ef[e * ST + o]);
        }
        atomicAdd(&agg[(size_t)cur * D + o], sum);
    }
    // segmented coord scatter
    if (tid < 6) {
        int c = tid % 3, q = tid / 3;
        int base = q * 64;
        float sum = 0.f;
        int cur = srcs[base];
        for (int k = 0; k < 64; ++k) {
            int e = base + k;
            int s = srcs[e];
            if (s != cur) {
                atomicAdd(&coord_out[(size_t)cur * 3 + c], sum);
                sum = 0.f; cur = s;
            }
            float cdv = (c == 0) ? cdx[e] : (c == 1) ? cdy[e] : cdz[e];
            sum += cdv * wco[e];
        }
        atomicAdd(&coord_out[(size_t)cur * 3 + c], sum);
    }
}

// ---------------- MFMA node kernel ----------------
__global__ __launch_bounds__(TPB)
void egcl_node(const float* __restrict__ h,
               const ushort* __restrict__ wn1b, const ushort* __restrict__ wn2b,
               const float* __restrict__ bn1, const float* __restrict__ bn2,
               float* __restrict__ hout /* holds agg on entry */)
{
    __shared__ __align__(16) ushort nin[EB * SA];
    __shared__ __align__(16) ushort t1 [EB * ST];
    __shared__ __align__(16) ushort wch[2][128 * SWC];
    __shared__ float b1s[H], b2s[H];

    const int tid  = threadIdx.x;
    const int lane = tid & 63;
    const int wv   = tid >> 6;
    const int eg   = wv >> 2;
    const int cg   = wv & 3;
    const int n0   = blockIdx.x * EB;

    if (tid < 128) b1s[tid] = bn1[tid];
    else if (tid < 256) b2s[tid - 128] = bn2[tid - 128];

    // stage nin = [h | agg] as bf16
    #pragma unroll
    for (int half = 0; half < 2; ++half) {
        const float* src = half ? hout : h;
        #pragma unroll
        for (int it = 0; it < 8; ++it) {
            int idx = tid + it * TPB;
            int e = idx >> 5, c = idx & 31;
            int n = n0 + e; if (n >= N_NODES) n = 0;
            float4 v = *(const float4*)&src[(size_t)n * D + c * 4];
            ushort4 p;
            p.x = f2b(v.x); p.y = f2b(v.y); p.z = f2b(v.z); p.w = f2b(v.w);
            *(ushort4*)&nin[e * SA + half * 128 + c * 4] = p;
        }
    }
    stage_wb(wch[0], wn1b, 256, 0, tid);
    __syncthreads();

    f32x4 acc[4][2];
    const int r = lane & 15, g = lane >> 4;

    zero_acc8(acc);
    for (int kc = 0; kc < 8; ++kc) {
        if (kc < 7) stage_wb(wch[(kc + 1) & 1], wn1b, 256, (kc + 1) * 32, tid);
        gemm_chunk(nin, SA, kc * 32, wch[kc & 1], acc, eg, cg, lane);
        __syncthreads();
    }
    epi_silu8(acc, b1s, t1, ST, eg, cg, lane);
    stage_wb(wch[0], wn2b, 128, 0, tid);
    __syncthreads();

    zero_acc8(acc);
    for (int kc = 0; kc < 4; ++kc) {
        if (kc < 3) stage_wb(wch[(kc + 1) & 1], wn2b, 128, (kc + 1) * 32, tid);
        gemm_chunk(t1, ST, kc * 32, wch[kc & 1], acc, eg, cg, lane);
        __syncthreads();
    }
    #pragma unroll
    for (int nt = 0; nt < 2; ++nt) {
        int o = cg * 32 + nt * 16 + r;
        float b = b2s[o];
        #pragma unroll
        for (int mt = 0; mt < 4; ++mt)
            #pragma unroll
            for (int j = 0; j < 4; ++j) {
                int n = n0 + eg * 64 + mt * 16 + g * 4 + j;
                if (n < N_NODES)
                    hout[(size_t)n * D + o] = h[(size_t)n * D + o] + acc[mt][nt][j] + b;
            }
    }
}

extern "C" void kernel_launch(void* const* d_in, const int* in_sizes, int n_in,
                              void* d_out, int out_size, void* d_ws, size_t ws_size,
                              hipStream_t stream)
{
    const float* h     = (const float*)d_in[0];
    const float* coord = (const float*)d_in[1];
    const int*   eidx  = (const int*)d_in[2];
    const float* We1 = (const float*)d_in[3];
    const float* be1 = (const float*)d_in[4];
    const float* We2 = (const float*)d_in[5];
    const float* be2 = (const float*)d_in[6];
    const float* Wn1 = (const float*)d_in[7];
    const float* bn1 = (const float*)d_in[8];
    const float* Wn2 = (const float*)d_in[9];
    const float* bn2 = (const float*)d_in[10];
    const float* Wc1 = (const float*)d_in[11];
    const float* bc1 = (const float*)d_in[12];
    const float* Wc2 = (const float*)d_in[13];

    float* hout = (float*)d_out;
    float* cout = (float*)d_out + (size_t)N_NODES * D;

    char* ws = (char*)d_ws;
    ushort* w1b  = (ushort*)(ws + WS_W1);
    ushort* w2b  = (ushort*)(ws + WS_W2);
    ushort* wc1b = (ushort*)(ws + WS_WC1);
    ushort* wn1b = (ushort*)(ws + WS_WN1);
    ushort* wn2b = (ushort*)(ws + WS_WN2);
    int* cnt  = (int*)(ws + WS_CNT);
    int* cur  = (int*)(ws + WS_CUR);
    int* perm = (int*)(ws + WS_PERM);

    int prep_tot = 114688 + N_NODES + N_NODES * D + N_NODES * 3;
    prep<<<(prep_tot + 255) / 256, 256, 0, stream>>>(We1, We2, Wc1, Wn1, Wn2, coord,
                                                     w1b, w2b, wc1b, wn1b, wn2b,
                                                     cnt, hout, cout);
    hist_k<<<(N_EDGES + 255) / 256, 256, 0, stream>>>(eidx, cnt);
    scan_k<<<1, 1024, 0, stream>>>(cnt, cur);
    scatter_k<<<(N_EDGES + 255) / 256, 256, 0, stream>>>(eidx, cur, perm);
    egcl_edge<<<N_EDGES / EB, TPB, 0, stream>>>(h, coord, eidx, perm,
                                                w1b, w2b, wc1b,
                                                We1, be1, be2, bc1, Wc2,
                                                hout, cout);
    egcl_node<<<(N_NODES + EB - 1) / EB, TPB, 0, stream>>>(h, wn1b, wn2b, bn1, bn2, hout);
}

// Round 4
// 490.665 us; speedup vs baseline: 8.0398x; 1.1582x over previous
//
#include <hip/hip_runtime.h>

#define N_NODES 20000
#define N_EDGES 640000
#define D 128
#define H 128

#define EB   128                 // edges (or nodes) per tile
#define TPB  512                 // 8 waves
#define NBLK 256                 // persistent edge blocks
#define NTILE (N_EDGES / EB)     // 5000
#define SA   264                 // ein row stride (bf16 shorts); 528B % 128 = 16 -> 2-way (free)
#define ST   136                 // t1/ef row stride; 272B % 128 = 16 -> 2-way (free)

// ---- workspace layout (bytes) ----
#define WS_W1   0                // We1[:, :256] bf16 [128][256]
#define WS_W2   65536            // We2 bf16 [128][128]
#define WS_WC1  98304            // Wc1 bf16 [128][128]
#define WS_WN1  131072           // Wn1 bf16 [128][256]
#define WS_WN2  196608           // Wn2 bf16 [128][128]
#define WS_CNT  229376           // int[20000]
#define WS_CUR  309376           // int[20000]
#define WS_PERM 389376           // int[640000]

typedef short bf16x8 __attribute__((ext_vector_type(8)));
typedef float f32x4  __attribute__((ext_vector_type(4)));

__device__ __forceinline__ float silu_f(float x) { return x / (1.0f + __expf(-x)); }

__device__ __forceinline__ ushort f2b(float f) {          // f32 -> bf16 RNE
    union { float f; unsigned int u; } v; v.f = f;
    return (ushort)((v.u + 0x7FFF + ((v.u >> 16) & 1)) >> 16);
}
__device__ __forceinline__ float b2f(ushort s) {
    union { unsigned int u; float f; } v; v.u = ((unsigned int)s) << 16; return v.f;
}

// one K=32 chunk with register-resident B: acc[4][2] += A[64x32] @ Breg
__device__ __forceinline__ void gemm_chunk_rw(const ushort* Ab, int astride, int kc0,
                                              const bf16x8 b[2], f32x4 acc[4][2],
                                              int eg, int lane)
{
    const int r = lane & 15, g = lane >> 4;
    bf16x8 a[4];
    #pragma unroll
    for (int mt = 0; mt < 4; ++mt)
        a[mt] = *(const bf16x8*)&Ab[(eg * 64 + mt * 16 + r) * astride + kc0 + g * 8];
    #pragma unroll
    for (int mt = 0; mt < 4; ++mt)
        #pragma unroll
        for (int nt = 0; nt < 2; ++nt)
            acc[mt][nt] = __builtin_amdgcn_mfma_f32_16x16x32_bf16(a[mt], b[nt], acc[mt][nt], 0, 0, 0);
}

__device__ __forceinline__ void zero_acc8(f32x4 acc[4][2]) {
    #pragma unroll
    for (int mt = 0; mt < 4; ++mt)
        #pragma unroll
        for (int nt = 0; nt < 2; ++nt)
            acc[mt][nt] = (f32x4){0.f, 0.f, 0.f, 0.f};
}

__device__ __forceinline__ void epi_silu8(f32x4 acc[4][2], const float* bias,
                                          ushort* out, int ostride,
                                          int eg, int cg, int lane) {
    const int r = lane & 15, g = lane >> 4;
    #pragma unroll
    for (int nt = 0; nt < 2; ++nt) {
        int o = cg * 32 + nt * 16 + r;
        float bo = bias[o];
        #pragma unroll
        for (int mt = 0; mt < 4; ++mt)
            #pragma unroll
            for (int j = 0; j < 4; ++j) {
                int e = eg * 64 + mt * 16 + g * 4 + j;
                out[e * ostride + o] = f2b(silu_f(acc[mt][nt][j] + bo));
            }
    }
}

// ---------------- prep: weight bf16 conversion + zeroing ----------------
__global__ void prep(const float* __restrict__ We1, const float* __restrict__ We2,
                     const float* __restrict__ Wc1, const float* __restrict__ Wn1,
                     const float* __restrict__ Wn2, const float* __restrict__ coord,
                     ushort* w1, ushort* w2, ushort* wc1, ushort* wn1, ushort* wn2,
                     int* cnt, float* hout, float* cout)
{
    int idx = blockIdx.x * 256 + threadIdx.x;
    if (idx < 32768) { w1[idx] = f2b(We1[(idx >> 8) * 257 + (idx & 255)]); return; }
    idx -= 32768;
    if (idx < 16384) { w2[idx] = f2b(We2[idx]); return; }
    idx -= 16384;
    if (idx < 16384) { wc1[idx] = f2b(Wc1[idx]); return; }
    idx -= 16384;
    if (idx < 32768) { wn1[idx] = f2b(Wn1[idx]); return; }
    idx -= 32768;
    if (idx < 16384) { wn2[idx] = f2b(Wn2[idx]); return; }
    idx -= 16384;
    if (idx < N_NODES) { cnt[idx] = 0; return; }
    idx -= N_NODES;
    if (idx < N_NODES * D) { hout[idx] = 0.f; return; }
    idx -= N_NODES * D;
    if (idx < N_NODES * 3) cout[idx] = coord[idx];
}

// ---------------- counting sort by src ----------------
__global__ void hist_k(const int* __restrict__ eidx, int* cnt) {
    int e = blockIdx.x * 256 + threadIdx.x;
    if (e < N_EDGES) atomicAdd(&cnt[eidx[e]], 1);
}

__global__ void scan_k(const int* __restrict__ cnt, int* cur) {
    __shared__ int buf[1024];
    __shared__ int carry_s;
    int t = threadIdx.x;
    if (t == 0) carry_s = 0;
    __syncthreads();
    for (int base = 0; base < N_NODES; base += 1024) {
        int v = (base + t < N_NODES) ? cnt[base + t] : 0;
        buf[t] = v; __syncthreads();
        for (int off = 1; off < 1024; off <<= 1) {
            int a = (t >= off) ? buf[t - off] : 0;
            __syncthreads();
            buf[t] += a;
            __syncthreads();
        }
        if (base + t < N_NODES) cur[base + t] = carry_s + buf[t] - v;
        __syncthreads();
        if (t == 0) carry_s += buf[1023];
        __syncthreads();
    }
}

__global__ void scatter_k(const int* __restrict__ eidx, int* cur, int* perm) {
    int e = blockIdx.x * 256 + threadIdx.x;
    if (e < N_EDGES) {
        int p = atomicAdd(&cur[eidx[e]], 1);
        perm[p] = e;
    }
}

// ---------------- fused edge kernel (persistent, register weights) ----------------
__global__ __launch_bounds__(TPB, 2)
void egcl_edge(const float* __restrict__ h, const float* __restrict__ coord,
               const int* __restrict__ eidx, const int* __restrict__ perm,
               const ushort* __restrict__ w1b, const ushort* __restrict__ w2b,
               const ushort* __restrict__ wc1b,
               const float* __restrict__ We1, const float* __restrict__ be1,
               const float* __restrict__ be2, const float* __restrict__ bc1,
               const float* __restrict__ Wc2,
               float* __restrict__ agg, float* __restrict__ coord_out)
{
    __shared__ __align__(16) ushort ein[EB * SA];        // ef overlays after GEMM1
    __shared__ __align__(16) ushort t1 [EB * ST];        // c1 overlays after GEMM2
    __shared__ float radial_f[EB], w256[H], b1s[H], b2s[H], bc1s[H], wc2s[H];
    __shared__ float cdx[EB], cdy[EB], cdz[EB], wco[EB];
    __shared__ int   srcs[EB], dsts[EB];

    ushort* const ef = ein;

    const int tid  = threadIdx.x;
    const int lane = tid & 63;
    const int wv   = tid >> 6;
    const int eg   = wv >> 2;
    const int cg   = wv & 3;
    const int r    = lane & 15, g = lane >> 4;

    // block-constant small vectors (once)
    if (tid < 128)      { w256[tid] = We1[tid * 257 + 256]; b1s[tid] = be1[tid]; }
    else if (tid < 256) { int o = tid - 128; b2s[o] = be2[o]; bc1s[o] = bc1[o]; }
    else if (tid < 384) { int o = tid - 256; wc2s[o] = Wc2[o]; }

    // ---- register-resident weight slices (once per block) ----
    bf16x8 w1f[8][2], w2f[4][2], w3f[4][2];
    {
        const int c0 = cg * 32 + r, c1 = c0 + 16;
        #pragma unroll
        for (int kc = 0; kc < 8; ++kc) {
            w1f[kc][0] = *(const bf16x8*)&w1b[c0 * 256 + kc * 32 + g * 8];
            w1f[kc][1] = *(const bf16x8*)&w1b[c1 * 256 + kc * 32 + g * 8];
        }
        #pragma unroll
        for (int kc = 0; kc < 4; ++kc) {
            w2f[kc][0] = *(const bf16x8*)&w2b [c0 * 128 + kc * 32 + g * 8];
            w2f[kc][1] = *(const bf16x8*)&w2b [c1 * 128 + kc * 32 + g * 8];
            w3f[kc][0] = *(const bf16x8*)&wc1b[c0 * 128 + kc * 32 + g * 8];
            w3f[kc][1] = *(const bf16x8*)&wc1b[c1 * 128 + kc * 32 + g * 8];
        }
    }

    // ---- prologue prefetch of first tile's indices ----
    int t = blockIdx.x;
    int pf_s = 0, pf_d = 0;
    float pf_sx = 0, pf_sy = 0, pf_sz = 0, pf_dx = 0, pf_dy = 0, pf_dz = 0;
    if (t < NTILE && tid < EB) {
        int e = perm[t * EB + tid];
        pf_s = eidx[e]; pf_d = eidx[N_EDGES + e];
        pf_sx = coord[pf_s * 3]; pf_sy = coord[pf_s * 3 + 1]; pf_sz = coord[pf_s * 3 + 2];
        pf_dx = coord[pf_d * 3]; pf_dy = coord[pf_d * 3 + 1]; pf_dz = coord[pf_d * 3 + 2];
    }

    f32x4 acc[4][2];

    for (; t < NTILE; t += NBLK) {
        // commit prefetched indices to LDS
        if (tid < EB) {
            srcs[tid] = pf_s; dsts[tid] = pf_d;
            float dx = pf_sx - pf_dx, dy = pf_sy - pf_dy, dz = pf_sz - pf_dz;
            cdx[tid] = dx; cdy[tid] = dy; cdz[tid] = dz;
            radial_f[tid] = dx * dx + dy * dy + dz * dz;
        }
        __syncthreads();                                   // (a) indices ready

        // issue next tile's perm load early (independent)
        const int tn = t + NBLK;
        int e_next = 0;
        if (tn < NTILE && tid < EB) e_next = perm[tn * EB + tid];

        // gather e_in = [h[src] | h[dst]] as bf16 (src sorted -> L1/L2 reuse)
        #pragma unroll
        for (int half = 0; half < 2; ++half) {
            #pragma unroll
            for (int it = 0; it < 8; ++it) {
                int idx = tid + it * TPB;
                int e = idx >> 5, c = idx & 31;
                int node = half ? dsts[e] : srcs[e];
                float4 v = *(const float4*)&h[(size_t)node * D + c * 4];
                ushort4 p;
                p.x = f2b(v.x); p.y = f2b(v.y); p.z = f2b(v.z); p.w = f2b(v.w);
                *(ushort4*)&ein[e * SA + half * 128 + c * 4] = p;
            }
        }
        // finish next-tile prefetch chain (overlaps gather latency)
        if (tn < NTILE && tid < EB) {
            pf_s = eidx[e_next]; pf_d = eidx[N_EDGES + e_next];
            pf_sx = coord[pf_s * 3]; pf_sy = coord[pf_s * 3 + 1]; pf_sz = coord[pf_s * 3 + 2];
            pf_dx = coord[pf_d * 3]; pf_dy = coord[pf_d * 3 + 1]; pf_dz = coord[pf_d * 3 + 2];
        }
        __syncthreads();                                   // (b) ein ready

        // GEMM1: ein[128x256] @ We1[:, :256]^T (register B, no inner barriers)
        zero_acc8(acc);
        #pragma unroll
        for (int kc = 0; kc < 8; ++kc)
            gemm_chunk_rw(ein, SA, kc * 32, w1f[kc], acc, eg, lane);
        #pragma unroll
        for (int nt = 0; nt < 2; ++nt) {                   // exact f32 radial rank-1
            int o = cg * 32 + nt * 16 + r;
            float w = w256[o];
            #pragma unroll
            for (int mt = 0; mt < 4; ++mt)
                #pragma unroll
                for (int j = 0; j < 4; ++j)
                    acc[mt][nt][j] += radial_f[eg * 64 + mt * 16 + g * 4 + j] * w;
        }
        epi_silu8(acc, b1s, t1, ST, eg, cg, lane);
        __syncthreads();                                   // (c) t1 ready (ein dead)

        // GEMM2: t1 @ We2^T -> ef (overlays ein)
        zero_acc8(acc);
        #pragma unroll
        for (int kc = 0; kc < 4; ++kc)
            gemm_chunk_rw(t1, ST, kc * 32, w2f[kc], acc, eg, lane);
        epi_silu8(acc, b2s, ef, ST, eg, cg, lane);
        __syncthreads();                                   // (d) ef ready (t1 dead)

        // GEMM3: ef @ Wc1^T -> c1 (overlays t1)
        zero_acc8(acc);
        #pragma unroll
        for (int kc = 0; kc < 4; ++kc)
            gemm_chunk_rw(ef, ST, kc * 32, w3f[kc], acc, eg, lane);
        epi_silu8(acc, bc1s, t1, ST, eg, cg, lane);
        __syncthreads();                                   // (e) c1 ready

        // wco[e] = c1[e] . Wc2
        {
            int e = tid >> 2, q = tid & 3;
            const ushort* c1r = &t1[e * ST + q * 32];
            float s_ = 0.f;
            #pragma unroll
            for (int k = 0; k < 32; ++k) s_ += b2f(c1r[k]) * wc2s[q * 32 + k];
            s_ += __shfl_down(s_, 2);
            s_ += __shfl_down(s_, 1);
            if (q == 0) wco[e] = s_;
        }
        __syncthreads();                                   // (f) wco ready

        // coord scatter (sorted srcs -> low contention)
        if (tid < 384) {
            int e = tid / 3, c = tid - (tid / 3) * 3;
            float cdv = (c == 0) ? cdx[e] : (c == 1) ? cdy[e] : cdz[e];
            atomicAdd(&coord_out[(size_t)srcs[e] * 3 + c], cdv * wco[e]);
        }
        // segmented agg scatter: 1 atomic per (run x col x 32-edge chunk)
        {
            int o = tid & 127, q = tid >> 7;
            int base = q * 32;
            float sum = 0.f;
            int cur = srcs[base];
            for (int k = 0; k < 32; ++k) {
                int e = base + k;
                int s = srcs[e];
                if (s != cur) {
                    atomicAdd(&agg[(size_t)cur * D + o], sum);
                    sum = 0.f; cur = s;
                }
                sum += b2f(ef[e * ST + o]);
            }
            atomicAdd(&agg[(size_t)cur * D + o], sum);
        }
        __syncthreads();                                   // (g) ef/srcs reusable
    }
}

// ---------------- MFMA node kernel (register weights) ----------------
__global__ __launch_bounds__(TPB, 2)
void egcl_node(const float* __restrict__ h,
               const ushort* __restrict__ wn1b, const ushort* __restrict__ wn2b,
               const float* __restrict__ bn1, const float* __restrict__ bn2,
               float* __restrict__ hout /* holds agg on entry */)
{
    __shared__ __align__(16) ushort nin[EB * SA];
    __shared__ __align__(16) ushort t1 [EB * ST];
    __shared__ float b1s[H], b2s[H];

    const int tid  = threadIdx.x;
    const int lane = tid & 63;
    const int wv   = tid >> 6;
    const int eg   = wv >> 2;
    const int cg   = wv & 3;
    const int r    = lane & 15, g = lane >> 4;
    const int n0   = blockIdx.x * EB;

    if (tid < 128) b1s[tid] = bn1[tid];
    else if (tid < 256) b2s[tid - 128] = bn2[tid - 128];

    bf16x8 w1f[8][2], w2f[4][2];
    {
        const int c0 = cg * 32 + r, c1 = c0 + 16;
        #pragma unroll
        for (int kc = 0; kc < 8; ++kc) {
            w1f[kc][0] = *(const bf16x8*)&wn1b[c0 * 256 + kc * 32 + g * 8];
            w1f[kc][1] = *(const bf16x8*)&wn1b[c1 * 256 + kc * 32 + g * 8];
        }
        #pragma unroll
        for (int kc = 0; kc < 4; ++kc) {
            w2f[kc][0] = *(const bf16x8*)&wn2b[c0 * 128 + kc * 32 + g * 8];
            w2f[kc][1] = *(const bf16x8*)&wn2b[c1 * 128 + kc * 32 + g * 8];
        }
    }

    // stage nin = [h | agg] as bf16
    #pragma unroll
    for (int half = 0; half < 2; ++half) {
        const float* src = half ? hout : h;
        #pragma unroll
        for (int it = 0; it < 8; ++it) {
            int idx = tid + it * TPB;
            int e = idx >> 5, c = idx & 31;
            int n = n0 + e; if (n >= N_NODES) n = 0;
            float4 v = *(const float4*)&src[(size_t)n * D + c * 4];
            ushort4 p;
            p.x = f2b(v.x); p.y = f2b(v.y); p.z = f2b(v.z); p.w = f2b(v.w);
            *(ushort4*)&nin[e * SA + half * 128 + c * 4] = p;
        }
    }
    __syncthreads();

    f32x4 acc[4][2];
    zero_acc8(acc);
    #pragma unroll
    for (int kc = 0; kc < 8; ++kc)
        gemm_chunk_rw(nin, SA, kc * 32, w1f[kc], acc, eg, lane);
    epi_silu8(acc, b1s, t1, ST, eg, cg, lane);
    __syncthreads();

    zero_acc8(acc);
    #pragma unroll
    for (int kc = 0; kc < 4; ++kc)
        gemm_chunk_rw(t1, ST, kc * 32, w2f[kc], acc, eg, lane);
    #pragma unroll
    for (int nt = 0; nt < 2; ++nt) {
        int o = cg * 32 + nt * 16 + r;
        float b = b2s[o];
        #pragma unroll
        for (int mt = 0; mt < 4; ++mt)
            #pragma unroll
            for (int j = 0; j < 4; ++j) {
                int n = n0 + eg * 64 + mt * 16 + g * 4 + j;
                if (n < N_NODES)
                    hout[(size_t)n * D + o] = h[(size_t)n * D + o] + acc[mt][nt][j] + b;
            }
    }
}

extern "C" void kernel_launch(void* const* d_in, const int* in_sizes, int n_in,
                              void* d_out, int out_size, void* d_ws, size_t ws_size,
                              hipStream_t stream)
{
    const float* h     = (const float*)d_in[0];
    const float* coord = (const float*)d_in[1];
    const int*   eidx  = (const int*)d_in[2];
    const float* We1 = (const float*)d_in[3];
    const float* be1 = (const float*)d_in[4];
    const float* We2 = (const float*)d_in[5];
    const float* be2 = (const float*)d_in[6];
    const float* Wn1 = (const float*)d_in[7];
    const float* bn1 = (const float*)d_in[8];
    const float* Wn2 = (const float*)d_in[9];
    const float* bn2 = (const float*)d_in[10];
    const float* Wc1 = (const float*)d_in[11];
    const float* bc1 = (const float*)d_in[12];
    const float* Wc2 = (const float*)d_in[13];

    float* hout = (float*)d_out;
    float* cout = (float*)d_out + (size_t)N_NODES * D;

    char* ws = (char*)d_ws;
    ushort* w1b  = (ushort*)(ws + WS_W1);
    ushort* w2b  = (ushort*)(ws + WS_W2);
    ushort* wc1b = (ushort*)(ws + WS_WC1);
    ushort* wn1b = (ushort*)(ws + WS_WN1);
    ushort* wn2b = (ushort*)(ws + WS_WN2);
    int* cnt  = (int*)(ws + WS_CNT);
    int* cur  = (int*)(ws + WS_CUR);
    int* perm = (int*)(ws + WS_PERM);

    int prep_tot = 114688 + N_NODES + N_NODES * D + N_NODES * 3;
    prep<<<(prep_tot + 255) / 256, 256, 0, stream>>>(We1, We2, Wc1, Wn1, Wn2, coord,
                                                     w1b, w2b, wc1b, wn1b, wn2b,
                                                     cnt, hout, cout);
    hist_k<<<(N_EDGES + 255) / 256, 256, 0, stream>>>(eidx, cnt);
    scan_k<<<1, 1024, 0, stream>>>(cnt, cur);
    scatter_k<<<(N_EDGES + 255) / 256, 256, 0, stream>>>(eidx, cur, perm);
    egcl_edge<<<NBLK, TPB, 0, stream>>>(h, coord, eidx, perm,
                                        w1b, w2b, wc1b,
                                        We1, be1, be2, bc1, Wc2,
                                        hout, cout);
    egcl_node<<<(N_NODES + EB - 1) / EB, TPB, 0, stream>>>(h, wn1b, wn2b, bn1, bn2, hout);
}

// Round 5
// 334.616 us; speedup vs baseline: 11.7891x; 1.4664x over previous
//
#include <hip/hip_runtime.h>

#define N_NODES 20000
#define N_EDGES 640000
#define D 128
#define H 128

#define EB   128                 // edges (or nodes) per tile
#define TPB  512                 // 8 waves
#define NBLK 256                 // persistent edge blocks
#define NTILE (N_EDGES / EB)     // 5000
#define NNT  ((N_NODES + EB - 1) / EB)  // 157 node tiles
#define ST   136                 // bf16 tile row stride; 272B % 128 = 16 -> ~2-way (free)

// ---- workspace layout (bytes) ----
#define WS_W1   0                // We1[:, :256] bf16 [128][256]
#define WS_W2   65536            // We2 bf16 [128][128]
#define WS_WC1  98304            // Wc1 bf16 [128][128]
#define WS_WN1  131072           // Wn1 bf16 [128][256]
#define WS_WN2  196608           // Wn2 bf16 [128][128]
#define WS_CNT  229376           // int[20000]
#define WS_CUR  309376           // int[20000]
#define WS_PERM 389376           // int[640000]
#define WS_U    2949376          // u bf16 [20000][128]
#define WS_V    8069376          // v bf16 [20000][128]
#define WS_P    13189376         // p bf16 [20000][128]   (ends ~18.3 MB)

typedef short bf16x8 __attribute__((ext_vector_type(8)));
typedef float f32x4  __attribute__((ext_vector_type(4)));

__device__ __forceinline__ float silu_f(float x) {
    return x * __builtin_amdgcn_rcpf(1.0f + __expf(-x));
}
__device__ __forceinline__ ushort f2b(float f) {          // f32 -> bf16 RNE
    union { float f; unsigned int u; } v; v.f = f;
    return (ushort)((v.u + 0x7FFF + ((v.u >> 16) & 1)) >> 16);
}
__device__ __forceinline__ float b2f(ushort s) {
    union { unsigned int u; float f; } v; v.u = ((unsigned int)s) << 16; return v.f;
}

// one K=32 chunk with register-resident B: acc[4][2] += A[64x32] @ Breg
__device__ __forceinline__ void gemm_chunk_rw(const ushort* Ab, int kc0,
                                              const bf16x8 b[2], f32x4 acc[4][2],
                                              int eg, int lane)
{
    const int r = lane & 15, g = lane >> 4;
    bf16x8 a[4];
    #pragma unroll
    for (int mt = 0; mt < 4; ++mt)
        a[mt] = *(const bf16x8*)&Ab[(eg * 64 + mt * 16 + r) * ST + kc0 + g * 8];
    #pragma unroll
    for (int mt = 0; mt < 4; ++mt)
        #pragma unroll
        for (int nt = 0; nt < 2; ++nt)
            acc[mt][nt] = __builtin_amdgcn_mfma_f32_16x16x32_bf16(a[mt], b[nt], acc[mt][nt], 0, 0, 0);
}

__device__ __forceinline__ void zero_acc8(f32x4 acc[4][2]) {
    #pragma unroll
    for (int mt = 0; mt < 4; ++mt)
        #pragma unroll
        for (int nt = 0; nt < 2; ++nt)
            acc[mt][nt] = (f32x4){0.f, 0.f, 0.f, 0.f};
}

__device__ __forceinline__ void epi_silu8(f32x4 acc[4][2], const float* bias,
                                          ushort* out, int eg, int cg, int lane) {
    const int r = lane & 15, g = lane >> 4;
    #pragma unroll
    for (int nt = 0; nt < 2; ++nt) {
        int o = cg * 32 + nt * 16 + r;
        float bo = bias[o];
        #pragma unroll
        for (int mt = 0; mt < 4; ++mt)
            #pragma unroll
            for (int j = 0; j < 4; ++j) {
                int e = eg * 64 + mt * 16 + g * 4 + j;
                out[e * ST + o] = f2b(silu_f(acc[mt][nt][j] + bo));
            }
    }
}

// ---------------- prep: weight bf16 conversion + zeroing ----------------
__global__ void prep(const float* __restrict__ We1, const float* __restrict__ We2,
                     const float* __restrict__ Wc1, const float* __restrict__ Wn1,
                     const float* __restrict__ Wn2, const float* __restrict__ coord,
                     ushort* w1, ushort* w2, ushort* wc1, ushort* wn1, ushort* wn2,
                     int* cnt, float* hout, float* cout)
{
    int idx = blockIdx.x * 256 + threadIdx.x;
    if (idx < 32768) { w1[idx] = f2b(We1[(idx >> 8) * 257 + (idx & 255)]); return; }
    idx -= 32768;
    if (idx < 16384) { w2[idx] = f2b(We2[idx]); return; }
    idx -= 16384;
    if (idx < 16384) { wc1[idx] = f2b(Wc1[idx]); return; }
    idx -= 16384;
    if (idx < 32768) { wn1[idx] = f2b(Wn1[idx]); return; }
    idx -= 32768;
    if (idx < 16384) { wn2[idx] = f2b(Wn2[idx]); return; }
    idx -= 16384;
    if (idx < N_NODES) { cnt[idx] = 0; return; }
    idx -= N_NODES;
    if (idx < N_NODES * D) { hout[idx] = 0.f; return; }
    idx -= N_NODES * D;
    if (idx < N_NODES * 3) cout[idx] = coord[idx];
}

// ---------------- node-side precompute: u = h@Wa^T+be1, v = h@Wb^T, p = h@Wn1a^T+bn1 ----
__global__ __launch_bounds__(TPB, 2)
void uvp_k(const float* __restrict__ h,
           const ushort* __restrict__ w1b, const ushort* __restrict__ wn1b,
           const float* __restrict__ be1, const float* __restrict__ bn1,
           ushort* __restrict__ u, ushort* __restrict__ v, ushort* __restrict__ p)
{
    __shared__ __align__(16) ushort hs[EB * ST];
    __shared__ float b1s[H], bn1s[H];

    const int tid = threadIdx.x, lane = tid & 63, wv = tid >> 6;
    const int eg = wv >> 2, cg = wv & 3;
    const int r = lane & 15, g = lane >> 4;
    const int n0 = blockIdx.x * EB;

    if (tid < 128) b1s[tid] = be1[tid];
    else if (tid < 256) bn1s[tid - 128] = bn1[tid - 128];

    bf16x8 wa[4][2], wb[4][2], wn[4][2];
    {
        const int c0 = cg * 32 + r, c1c = c0 + 16;
        #pragma unroll
        for (int kc = 0; kc < 4; ++kc) {
            wa[kc][0] = *(const bf16x8*)&w1b [c0  * 256 +       kc * 32 + g * 8];
            wa[kc][1] = *(const bf16x8*)&w1b [c1c * 256 +       kc * 32 + g * 8];
            wb[kc][0] = *(const bf16x8*)&w1b [c0  * 256 + 128 + kc * 32 + g * 8];
            wb[kc][1] = *(const bf16x8*)&w1b [c1c * 256 + 128 + kc * 32 + g * 8];
            wn[kc][0] = *(const bf16x8*)&wn1b[c0  * 256 +       kc * 32 + g * 8];
            wn[kc][1] = *(const bf16x8*)&wn1b[c1c * 256 +       kc * 32 + g * 8];
        }
    }
    #pragma unroll
    for (int it = 0; it < 8; ++it) {
        int idx = tid + it * TPB;
        int e = idx >> 5, c = idx & 31;
        int n = n0 + e; if (n >= N_NODES) n = 0;
        float4 vv = *(const float4*)&h[(size_t)n * D + c * 4];
        ushort4 pk; pk.x = f2b(vv.x); pk.y = f2b(vv.y); pk.z = f2b(vv.z); pk.w = f2b(vv.w);
        *(ushort4*)&hs[e * ST + c * 4] = pk;
    }
    __syncthreads();

    f32x4 acc[4][2];
    // u = h @ Wa^T + be1
    zero_acc8(acc);
    #pragma unroll
    for (int kc = 0; kc < 4; ++kc) gemm_chunk_rw(hs, kc * 32, wa[kc], acc, eg, lane);
    #pragma unroll
    for (int nt = 0; nt < 2; ++nt) {
        int o = cg * 32 + nt * 16 + r;
        float bo = b1s[o];
        #pragma unroll
        for (int mt = 0; mt < 4; ++mt)
            #pragma unroll
            for (int j = 0; j < 4; ++j) {
                int n = n0 + eg * 64 + mt * 16 + g * 4 + j;
                if (n < N_NODES) u[(size_t)n * H + o] = f2b(acc[mt][nt][j] + bo);
            }
    }
    // v = h @ Wb^T
    zero_acc8(acc);
    #pragma unroll
    for (int kc = 0; kc < 4; ++kc) gemm_chunk_rw(hs, kc * 32, wb[kc], acc, eg, lane);
    #pragma unroll
    for (int nt = 0; nt < 2; ++nt) {
        int o = cg * 32 + nt * 16 + r;
        #pragma unroll
        for (int mt = 0; mt < 4; ++mt)
            #pragma unroll
            for (int j = 0; j < 4; ++j) {
                int n = n0 + eg * 64 + mt * 16 + g * 4 + j;
                if (n < N_NODES) v[(size_t)n * H + o] = f2b(acc[mt][nt][j]);
            }
    }
    // p = h @ Wn1[:, :128]^T + bn1
    zero_acc8(acc);
    #pragma unroll
    for (int kc = 0; kc < 4; ++kc) gemm_chunk_rw(hs, kc * 32, wn[kc], acc, eg, lane);
    #pragma unroll
    for (int nt = 0; nt < 2; ++nt) {
        int o = cg * 32 + nt * 16 + r;
        float bo = bn1s[o];
        #pragma unroll
        for (int mt = 0; mt < 4; ++mt)
            #pragma unroll
            for (int j = 0; j < 4; ++j) {
                int n = n0 + eg * 64 + mt * 16 + g * 4 + j;
                if (n < N_NODES) p[(size_t)n * H + o] = f2b(acc[mt][nt][j] + bo);
            }
    }
}

// ---------------- counting sort by src ----------------
__global__ void hist_k(const int* __restrict__ eidx, int* cnt) {
    int e = blockIdx.x * 256 + threadIdx.x;
    if (e < N_EDGES) atomicAdd(&cnt[eidx[e]], 1);
}

__global__ void scan_k(const int* __restrict__ cnt, int* cur) {
    __shared__ int wsum[16];
    __shared__ int carry_s;
    const int t = threadIdx.x, lane = t & 63, wid = t >> 6;
    if (t == 0) carry_s = 0;
    __syncthreads();
    for (int base = 0; base < N_NODES; base += 1024) {
        int i = base + t;
        int vv = (i < N_NODES) ? cnt[i] : 0;
        int s = vv;
        #pragma unroll
        for (int d = 1; d < 64; d <<= 1) {
            int x = __shfl_up(s, d);
            if (lane >= d) s += x;
        }
        if (lane == 63) wsum[wid] = s;
        __syncthreads();
        if (wid == 0) {
            int ws = (lane < 16) ? wsum[lane] : 0;
            #pragma unroll
            for (int d = 1; d < 16; d <<= 1) {
                int x = __shfl_up(ws, d);
                if (lane >= d) ws += x;
            }
            if (lane < 16) wsum[lane] = ws;
        }
        __syncthreads();
        int woff = (wid > 0) ? wsum[wid - 1] : 0;
        if (i < N_NODES) cur[i] = carry_s + woff + s - vv;
        __syncthreads();
        if (t == 0) carry_s += wsum[15];
        __syncthreads();
    }
}

__global__ void scatter_k(const int* __restrict__ eidx, int* cur, int* perm) {
    int e = blockIdx.x * 256 + threadIdx.x;
    if (e < N_EDGES) {
        int pp = atomicAdd(&cur[eidx[e]], 1);
        perm[pp] = e;
    }
}

// ---------------- fused edge kernel (persistent, pipelined) ----------------
__global__ __launch_bounds__(TPB, 2)
void egcl_edge(const ushort* __restrict__ u, const ushort* __restrict__ v,
               const int* __restrict__ eidx, const int* __restrict__ perm,
               const float* __restrict__ coordp,
               const ushort* __restrict__ w2b, const ushort* __restrict__ wc1b,
               const float* __restrict__ We1,
               const float* __restrict__ be2, const float* __restrict__ bc1,
               const float* __restrict__ Wc2,
               float* __restrict__ agg, float* __restrict__ coord_out)
{
    __shared__ __align__(16) ushort t1[EB * ST];
    __shared__ __align__(16) ushort ef[EB * ST];
    __shared__ __align__(16) ushort c1[EB * ST];
    __shared__ int   srcs_s[2][EB], dsts_s[2][EB];
    __shared__ float radial_s[2][EB];
    __shared__ float cdx_s[2][EB], cdy_s[2][EB], cdz_s[2][EB];
    __shared__ float wco[EB], b2s[H], bc1s[H], wc2s[H];

    const int tid = threadIdx.x, lane = tid & 63, wv = tid >> 6;
    const int eg = wv >> 2, cg = wv & 3;
    const int r = lane & 15, g = lane >> 4;
    const int ce = tid >> 2, cq = tid & 3;     // commit mapping: edge, col-quarter

    if (tid < 128) b2s[tid] = be2[tid];
    else if (tid < 256) bc1s[tid - 128] = bc1[tid - 128];
    else if (tid < 384) wc2s[tid - 256] = Wc2[tid - 256];

    // register weights for GEMM2/GEMM3 (64 VGPR)
    bf16x8 w2f[4][2], w3f[4][2];
    {
        const int c0 = cg * 32 + r, c1c = c0 + 16;
        #pragma unroll
        for (int kc = 0; kc < 4; ++kc) {
            w2f[kc][0] = *(const bf16x8*)&w2b [c0  * 128 + kc * 32 + g * 8];
            w2f[kc][1] = *(const bf16x8*)&w2b [c1c * 128 + kc * 32 + g * 8];
            w3f[kc][0] = *(const bf16x8*)&wc1b[c0  * 128 + kc * 32 + g * 8];
            w3f[kc][1] = *(const bf16x8*)&wc1b[c1c * 128 + kc * 32 + g * 8];
        }
    }
    // radial weight column (per commit-col set), f32 exact
    float w256a[32];
    #pragma unroll
    for (int i = 0; i < 32; ++i) w256a[i] = We1[(cq * 32 + i) * 257 + 256];

    // ---- prologue: chain tile t, commit; issue uv(t); chain t+NBLK ----
    int t = (int)blockIdx.x;
    int rs = 0, rd = 0;
    float rsx = 0, rsy = 0, rsz = 0, rdx = 0, rdy = 0, rdz = 0;
    if (tid < EB) {
        int e = perm[t * EB + tid];
        rs = eidx[e]; rd = eidx[N_EDGES + e];
        rsx = coordp[rs * 3]; rsy = coordp[rs * 3 + 1]; rsz = coordp[rs * 3 + 2];
        rdx = coordp[rd * 3]; rdy = coordp[rd * 3 + 1]; rdz = coordp[rd * 3 + 2];
        srcs_s[0][tid] = rs; dsts_s[0][tid] = rd;
        float dx = rsx - rdx, dy = rsy - rdy, dz = rsz - rdz;
        cdx_s[0][tid] = dx; cdy_s[0][tid] = dy; cdz_s[0][tid] = dz;
        radial_s[0][tid] = dx * dx + dy * dy + dz * dz;
    }
    __syncthreads();

    bf16x8 uvr[8];
    {
        const ushort* up = u + (size_t)srcs_s[0][ce] * H + cq * 32;
        const ushort* vp = v + (size_t)dsts_s[0][ce] * H + cq * 32;
        #pragma unroll
        for (int i = 0; i < 4; ++i) {
            uvr[i]     = *(const bf16x8*)(up + i * 8);
            uvr[4 + i] = *(const bf16x8*)(vp + i * 8);
        }
    }
    {   // full chain for t+NBLK (one-time)
        int tn = t + NBLK;
        rs = rd = 0; rsx = rsy = rsz = rdx = rdy = rdz = 0.f;
        if (tid < EB && tn < NTILE) {
            int e = perm[tn * EB + tid];
            rs = eidx[e]; rd = eidx[N_EDGES + e];
            rsx = coordp[rs * 3]; rsy = coordp[rs * 3 + 1]; rsz = coordp[rs * 3 + 2];
            rdx = coordp[rd * 3]; rdy = coordp[rd * 3 + 1]; rdz = coordp[rd * 3 + 2];
        }
    }

    f32x4 acc[4][2];
    int pb = 0;
    int en = 0, rs2 = 0, rd2 = 0;

    for (; t < NTILE; t += NBLK) {
        // ---- p0: commit uvr -> t1 (silu(u+v+radial*w)); commit idxregs -> idxLDS[pb^1]
        {
            float rad = radial_s[pb][ce];
            #pragma unroll
            for (int i = 0; i < 4; ++i) {
                bf16x8 uu = uvr[i], vx = uvr[4 + i];
                bf16x8 res;
                #pragma unroll
                for (int k = 0; k < 8; ++k) {
                    float x = b2f((ushort)uu[k]) + b2f((ushort)vx[k]) + rad * w256a[i * 8 + k];
                    res[k] = (short)f2b(silu_f(x));
                }
                *(bf16x8*)&t1[ce * ST + cq * 32 + i * 8] = res;
            }
        }
        if (tid < EB) {
            srcs_s[pb ^ 1][tid] = rs; dsts_s[pb ^ 1][tid] = rd;
            float dx = rsx - rdx, dy = rsy - rdy, dz = rsz - rdz;
            cdx_s[pb ^ 1][tid] = dx; cdy_s[pb ^ 1][tid] = dy; cdz_s[pb ^ 1][tid] = dz;
            radial_s[pb ^ 1][tid] = dx * dx + dy * dy + dz * dz;
        }
        __syncthreads();                                   // A: t1 + idx[pb^1] ready

        // ---- p1: issue uv loads for next tile; perm for t+2*NBLK; GEMM2 t1->ef
        {
            const ushort* up = u + (size_t)srcs_s[pb ^ 1][ce] * H + cq * 32;
            const ushort* vp = v + (size_t)dsts_s[pb ^ 1][ce] * H + cq * 32;
            #pragma unroll
            for (int i = 0; i < 4; ++i) {
                uvr[i]     = *(const bf16x8*)(up + i * 8);
                uvr[4 + i] = *(const bf16x8*)(vp + i * 8);
            }
        }
        {
            int tn = t + 2 * NBLK;
            en = 0;
            if (tid < EB && tn < NTILE) en = perm[tn * EB + tid];
        }
        zero_acc8(acc);
        #pragma unroll
        for (int kc = 0; kc < 4; ++kc) gemm_chunk_rw(t1, kc * 32, w2f[kc], acc, eg, lane);
        epi_silu8(acc, b2s, ef, eg, cg, lane);
        __syncthreads();                                   // B: ef ready

        // ---- p2: eidx segment of chain; GEMM3 ef->c1
        if (tid < EB) { rs2 = eidx[en]; rd2 = eidx[N_EDGES + en]; }
        zero_acc8(acc);
        #pragma unroll
        for (int kc = 0; kc < 4; ++kc) gemm_chunk_rw(ef, kc * 32, w3f[kc], acc, eg, lane);
        epi_silu8(acc, bc1s, c1, eg, cg, lane);
        __syncthreads();                                   // C: c1 ready

        // ---- p3: coord segment of chain; wco = c1 . Wc2
        if (tid < EB) {
            rs = rs2; rd = rd2;
            rsx = coordp[rs * 3]; rsy = coordp[rs * 3 + 1]; rsz = coordp[rs * 3 + 2];
            rdx = coordp[rd * 3]; rdy = coordp[rd * 3 + 1]; rdz = coordp[rd * 3 + 2];
        }
        {
            const ushort* c1r = &c1[ce * ST + cq * 32];
            float s_ = 0.f;
            #pragma unroll
            for (int k = 0; k < 32; ++k) s_ += b2f(c1r[k]) * wc2s[cq * 32 + k];
            s_ += __shfl_down(s_, 2);
            s_ += __shfl_down(s_, 1);
            if (cq == 0) wco[ce] = s_;
        }
        __syncthreads();                                   // D: wco ready

        // ---- p4: scatters ----
        if (tid < 384) {
            int e = tid / 3, c = tid - (tid / 3) * 3;
            float cdv = (c == 0) ? cdx_s[pb][e] : (c == 1) ? cdy_s[pb][e] : cdz_s[pb][e];
            atomicAdd(&coord_out[(size_t)srcs_s[pb][e] * 3 + c], cdv * wco[e]);
        }
        {
            int o = tid & 127, q = tid >> 7;
            int base = q * 32;
            float sum = 0.f;
            int cur = srcs_s[pb][base];
            for (int k = 0; k < 32; ++k) {
                int e = base + k;
                int s = srcs_s[pb][e];
                if (s != cur) {
                    atomicAdd(&agg[(size_t)cur * D + o], sum);
                    sum = 0.f; cur = s;
                }
                sum += b2f(ef[e * ST + o]);
            }
            atomicAdd(&agg[(size_t)cur * D + o], sum);
        }
        __syncthreads();                                   // E: ef/idx[pb] reusable
        pb ^= 1;
    }
}

// ---------------- node kernel: h_out = h + Wn2 @ silu(p + agg@Wn1b^T) + bn2 ----
__global__ __launch_bounds__(TPB, 2)
void egcl_node(const float* __restrict__ h,
               const ushort* __restrict__ wn1b, const ushort* __restrict__ wn2b,
               const ushort* __restrict__ pArr, const float* __restrict__ bn2,
               float* __restrict__ hout /* holds agg on entry */)
{
    __shared__ __align__(16) ushort t1[EB * ST];
    __shared__ __align__(16) ushort t2[EB * ST];
    __shared__ float b2s[H];

    const int tid = threadIdx.x, lane = tid & 63, wv = tid >> 6;
    const int eg = wv >> 2, cg = wv & 3;
    const int r = lane & 15, g = lane >> 4;
    const int n0 = blockIdx.x * EB;

    if (tid < 128) b2s[tid] = bn2[tid];

    bf16x8 wnb[4][2], w2f[4][2];
    {
        const int c0 = cg * 32 + r, c1c = c0 + 16;
        #pragma unroll
        for (int kc = 0; kc < 4; ++kc) {
            wnb[kc][0] = *(const bf16x8*)&wn1b[c0  * 256 + 128 + kc * 32 + g * 8];
            wnb[kc][1] = *(const bf16x8*)&wn1b[c1c * 256 + 128 + kc * 32 + g * 8];
            w2f[kc][0] = *(const bf16x8*)&wn2b[c0  * 128 + kc * 32 + g * 8];
            w2f[kc][1] = *(const bf16x8*)&wn2b[c1c * 128 + kc * 32 + g * 8];
        }
    }
    // stage agg as bf16
    #pragma unroll
    for (int it = 0; it < 8; ++it) {
        int idx = tid + it * TPB;
        int e = idx >> 5, c = idx & 31;
        int n = n0 + e; if (n >= N_NODES) n = 0;
        float4 vv = *(const float4*)&hout[(size_t)n * D + c * 4];
        ushort4 pk; pk.x = f2b(vv.x); pk.y = f2b(vv.y); pk.z = f2b(vv.z); pk.w = f2b(vv.w);
        *(ushort4*)&t1[e * ST + c * 4] = pk;
    }
    __syncthreads();

    f32x4 acc[4][2];
    zero_acc8(acc);
    #pragma unroll
    for (int kc = 0; kc < 4; ++kc) gemm_chunk_rw(t1, kc * 32, wnb[kc], acc, eg, lane);
    // epi: silu(acc + p[n][o]) -> t2
    #pragma unroll
    for (int nt = 0; nt < 2; ++nt) {
        int o = cg * 32 + nt * 16 + r;
        #pragma unroll
        for (int mt = 0; mt < 4; ++mt)
            #pragma unroll
            for (int j = 0; j < 4; ++j) {
                int e = eg * 64 + mt * 16 + g * 4 + j;
                int n = n0 + e; if (n >= N_NODES) n = 0;
                float x = acc[mt][nt][j] + b2f(pArr[(size_t)n * H + o]);
                t2[e * ST + o] = f2b(silu_f(x));
            }
    }
    __syncthreads();

    zero_acc8(acc);
    #pragma unroll
    for (int kc = 0; kc < 4; ++kc) gemm_chunk_rw(t2, kc * 32, w2f[kc], acc, eg, lane);
    #pragma unroll
    for (int nt = 0; nt < 2; ++nt) {
        int o = cg * 32 + nt * 16 + r;
        float bo = b2s[o];
        #pragma unroll
        for (int mt = 0; mt < 4; ++mt)
            #pragma unroll
            for (int j = 0; j < 4; ++j) {
                int n = n0 + eg * 64 + mt * 16 + g * 4 + j;
                if (n < N_NODES)
                    hout[(size_t)n * D + o] = h[(size_t)n * D + o] + acc[mt][nt][j] + bo;
            }
    }
}

extern "C" void kernel_launch(void* const* d_in, const int* in_sizes, int n_in,
                              void* d_out, int out_size, void* d_ws, size_t ws_size,
                              hipStream_t stream)
{
    const float* h     = (const float*)d_in[0];
    const float* coord = (const float*)d_in[1];
    const int*   eidx  = (const int*)d_in[2];
    const float* We1 = (const float*)d_in[3];
    const float* be1 = (const float*)d_in[4];
    const float* We2 = (const float*)d_in[5];
    const float* be2 = (const float*)d_in[6];
    const float* Wn1 = (const float*)d_in[7];
    const float* bn1 = (const float*)d_in[8];
    const float* Wn2 = (const float*)d_in[9];
    const float* bn2 = (const float*)d_in[10];
    const float* Wc1 = (const float*)d_in[11];
    const float* bc1 = (const float*)d_in[12];
    const float* Wc2 = (const float*)d_in[13];

    float* hout = (float*)d_out;                       // h_out; doubles as agg accumulator
    float* cout = (float*)d_out + (size_t)N_NODES * D; // coord_out

    char* ws = (char*)d_ws;
    ushort* w1b  = (ushort*)(ws + WS_W1);
    ushort* w2b  = (ushort*)(ws + WS_W2);
    ushort* wc1b = (ushort*)(ws + WS_WC1);
    ushort* wn1b = (ushort*)(ws + WS_WN1);
    ushort* wn2b = (ushort*)(ws + WS_WN2);
    int* cnt  = (int*)(ws + WS_CNT);
    int* cur  = (int*)(ws + WS_CUR);
    int* perm = (int*)(ws + WS_PERM);
    ushort* uArr = (ushort*)(ws + WS_U);
    ushort* vArr = (ushort*)(ws + WS_V);
    ushort* pArr = (ushort*)(ws + WS_P);

    int prep_tot = 114688 + N_NODES + N_NODES * D + N_NODES * 3;
    prep<<<(prep_tot + 255) / 256, 256, 0, stream>>>(We1, We2, Wc1, Wn1, Wn2, coord,
                                                     w1b, w2b, wc1b, wn1b, wn2b,
                                                     cnt, hout, cout);
    uvp_k<<<NNT, TPB, 0, stream>>>(h, w1b, wn1b, be1, bn1, uArr, vArr, pArr);
    hist_k<<<(N_EDGES + 255) / 256, 256, 0, stream>>>(eidx, cnt);
    scan_k<<<1, 1024, 0, stream>>>(cnt, cur);
    scatter_k<<<(N_EDGES + 255) / 256, 256, 0, stream>>>(eidx, cur, perm);
    egcl_edge<<<NBLK, TPB, 0, stream>>>(uArr, vArr, eidx, perm, coord,
                                        w2b, wc1b, We1, be2, bc1, Wc2,
                                        hout, cout);
    egcl_node<<<NNT, TPB, 0, stream>>>(h, wn1b, wn2b, pArr, bn2, hout);
}